// Round 2
// baseline (677.546 us; speedup 1.0000x reference)
//
#include <hip/hip_runtime.h>

// Problem: B=8, N=1024, C=512, H=8, dh=64.
// out = lin_bn_relu_p( relu( SCALE * Q @ (K^T V) ) ), Q/K/V = lin_bn_relu(x)
// (no softmax -> attention reassociates; K^T V is 64x64 per (b,h))
//
// ROUND 2 = CORRECTNESS PROBE: all-VALU fp32 accumulation, simple indexing,
// plus runtime dtype detection (bf16 vs fp32 device tensors).

#define CDIM  512
#define NSEQ  1024
#define MROWS 8192   // B*N

__device__ __forceinline__ float b2f(ushort u) {
    union { uint i; float f; } v; v.i = ((uint)u) << 16; return v.f;
}
__device__ __forceinline__ ushort f2b(float f) {
    union { float f; uint i; } v; v.f = f;
    uint u = v.i;
    u = u + 0x7fffu + ((u >> 16) & 1u);   // round-to-nearest-even
    return (ushort)(u >> 16);
}
// flagged load: f32 != 0 -> buffer holds fp32, else bf16 (ushort)
__device__ __forceinline__ float ldv(const void* p, long i, int f32) {
    return f32 ? ((const float*)p)[i] : b2f(((const ushort*)p)[i]);
}

// ---------------------------------------------------------------------------
// Dtype detector: interpret first 2048 ushorts of x as bf16. True-bf16 N(0,1)
// data never has exponent >= 0xC8 (|v| >= 2^73); fp32 data misread as bf16
// has ~21% such values (mantissa bits land in the exponent field).
// ---------------------------------------------------------------------------
__global__ void detect_kernel(const ushort* __restrict__ x, int* __restrict__ flag) {
    __shared__ int cnt;
    if (threadIdx.x == 0) cnt = 0;
    __syncthreads();
    int c = 0;
    for (int i = threadIdx.x; i < 2048; i += 256) {
        uint e = ((uint)x[i] >> 7) & 0xffu;
        if (e >= 0xC8u) ++c;
    }
    atomicAdd(&cnt, c);
    __syncthreads();
    if (threadIdx.x == 0) *flag = (cnt > 32) ? 1 : 0;
}

// ---------------------------------------------------------------------------
// Fold BatchNorm: s = g/sqrt(var+eps); t = (b-mu)*s + beta   (fp32, 2048 ch)
// ---------------------------------------------------------------------------
struct BnArgs {
    const void* b[4]; const void* g[4]; const void* be[4];
    const void* mu[4]; const void* va[4];
};

__global__ void prep_st_kernel(BnArgs a, float* __restrict__ s_all,
                               float* __restrict__ t_all,
                               const int* __restrict__ flag) {
    int f32 = *flag;
    int idx = blockIdx.x * 256 + threadIdx.x;   // 0..2047
    int br = idx >> 9, c = idx & 511;
    float g  = ldv(a.g[br],  c, f32);
    float be = ldv(a.be[br], c, f32);
    float mu = ldv(a.mu[br], c, f32);
    float va = ldv(a.va[br], c, f32);
    float bb = ldv(a.b[br],  c, f32);
    float s = g / sqrtf(va + 1e-5f);
    s_all[idx] = s;
    t_all[idx] = (bb - mu) * s + be;
}

// ---------------------------------------------------------------------------
// VALU GEMM: O = relu((A @ Bw^T)*s + t). A:[M,512], Bw:[512,512] ([out][in]).
// 64x64 tile, 256 threads (16x16), 4x4 micro-tile, fp32 accum, LDS-staged.
// a_flagged/o_flagged: whether A / O live in d_in/d_out (dtype per flag)
// vs workspace (always bf16).
// ---------------------------------------------------------------------------
__global__ __launch_bounds__(256) void gemm_valu(
    const void* __restrict__ A, const void* __restrict__ Bw, void* __restrict__ O,
    const float* __restrict__ s_all, const float* __restrict__ t_all, int st_off,
    const int* __restrict__ flag, int a_flagged, int o_flagged)
{
    __shared__ float As[64][33];
    __shared__ float Bs[64][33];
    int f32 = *flag;
    int af32 = f32 & a_flagged;
    int of32 = f32 & o_flagged;
    int t = threadIdx.x, ty = t >> 4, tx = t & 15;
    long row0 = (long)blockIdx.x * 64;
    int  col0 = blockIdx.y * 64;

    float acc[4][4] = {};
    for (int k0 = 0; k0 < CDIM; k0 += 32) {
        #pragma unroll
        for (int m = 0; m < 8; ++m) {
            int e = t + m * 256, r = e >> 5, c = e & 31;
            As[r][c] = ldv(A,  (row0 + r) * CDIM + k0 + c, af32);
            Bs[r][c] = ldv(Bw, (long)(col0 + r) * CDIM + k0 + c, f32);
        }
        __syncthreads();
        #pragma unroll 4
        for (int kk = 0; kk < 32; ++kk) {
            float av[4], bv[4];
            #pragma unroll
            for (int i = 0; i < 4; ++i) av[i] = As[ty * 4 + i][kk];
            #pragma unroll
            for (int j = 0; j < 4; ++j) bv[j] = Bs[tx * 4 + j][kk];
            #pragma unroll
            for (int i = 0; i < 4; ++i)
                #pragma unroll
                for (int j = 0; j < 4; ++j)
                    acc[i][j] += av[i] * bv[j];
        }
        __syncthreads();
    }
    #pragma unroll
    for (int j = 0; j < 4; ++j) {
        int col = col0 + tx * 4 + j;
        float s = s_all[st_off + col], tt = t_all[st_off + col];
        #pragma unroll
        for (int i = 0; i < 4; ++i) {
            long r = row0 + ty * 4 + i;
            float v = acc[i][j] * s + tt;
            v = v > 0.f ? v : 0.f;
            if (of32) ((float*)O)[r * CDIM + col] = v;
            else      ((ushort*)O)[r * CDIM + col] = f2b(v);
        }
    }
}

// ---------------------------------------------------------------------------
// S[bh][d1][d2] = sum_n K[b,n,h*64+d1] * V[b,n,h*64+d2]   (fp32 out, 64 blocks)
// K,V are workspace bf16 (always).
// ---------------------------------------------------------------------------
__global__ __launch_bounds__(256) void ktv_kernel(
    const ushort* __restrict__ K, const ushort* __restrict__ V,
    float* __restrict__ S)
{
    int bh = blockIdx.x, b = bh >> 3, h = bh & 7;
    __shared__ float Ks[8][64];
    __shared__ float Vs[8][64];
    int t = threadIdx.x;
    int lr = t >> 5, lc = (t & 31) * 2;
    int r0 = (t >> 4) * 4, c0 = (t & 15) * 4;
    const ushort* Kb = K + (long)b * NSEQ * CDIM + h * 64;
    const ushort* Vb = V + (long)b * NSEQ * CDIM + h * 64;

    float acc[4][4] = {};
    for (int it = 0; it < 128; ++it) {
        __syncthreads();
        long n = it * 8 + lr;
        Ks[lr][lc]     = b2f(Kb[n * CDIM + lc]);
        Ks[lr][lc + 1] = b2f(Kb[n * CDIM + lc + 1]);
        Vs[lr][lc]     = b2f(Vb[n * CDIM + lc]);
        Vs[lr][lc + 1] = b2f(Vb[n * CDIM + lc + 1]);
        __syncthreads();
        #pragma unroll
        for (int nn = 0; nn < 8; ++nn) {
            float kf[4], vf[4];
            #pragma unroll
            for (int i = 0; i < 4; ++i) kf[i] = Ks[nn][r0 + i];
            #pragma unroll
            for (int j = 0; j < 4; ++j) vf[j] = Vs[nn][c0 + j];
            #pragma unroll
            for (int i = 0; i < 4; ++i)
                #pragma unroll
                for (int j = 0; j < 4; ++j)
                    acc[i][j] += kf[i] * vf[j];
        }
    }
    float* out = S + ((long)bh * 64 + r0) * 64 + c0;
    #pragma unroll
    for (int i = 0; i < 4; ++i)
        #pragma unroll
        for (int j = 0; j < 4; ++j)
            out[i * 64 + j] = acc[i][j];
}

// ---------------------------------------------------------------------------
// In-place attention: Q[b, m, h*64+d2] <- relu(0.125 * sum_d1 Q[..d1]*S[d1][d2])
// Block = (bh, 64-row chunk). Q tile staged to LDS before overwrite -> safe.
// ---------------------------------------------------------------------------
__global__ __launch_bounds__(256) void attn_kernel(
    ushort* __restrict__ Q, const float* __restrict__ S)
{
    int bh = blockIdx.x, b = bh >> 3, h = bh & 7;
    int m0 = blockIdx.y * 64;
    __shared__ float Ss[64][64];
    __shared__ float Qs[64][65];
    int t = threadIdx.x, ty = t >> 4, tx = t & 15;

    for (int e = t; e < 4096; e += 256)
        Ss[e >> 6][e & 63] = S[(long)bh * 4096 + e];
    ushort* Qb = Q + ((long)(b * NSEQ + m0)) * CDIM + h * 64;
    for (int e = t; e < 4096; e += 256) {
        int r = e >> 6, c = e & 63;
        Qs[r][c] = b2f(Qb[(long)r * CDIM + c]);
    }
    __syncthreads();

    float acc[4][4] = {};
    for (int d1 = 0; d1 < 64; ++d1) {
        float qv[4], sv[4];
        #pragma unroll
        for (int i = 0; i < 4; ++i) qv[i] = Qs[ty * 4 + i][d1];
        #pragma unroll
        for (int j = 0; j < 4; ++j) sv[j] = Ss[d1][tx * 4 + j];
        #pragma unroll
        for (int i = 0; i < 4; ++i)
            #pragma unroll
            for (int j = 0; j < 4; ++j)
                acc[i][j] += qv[i] * sv[j];
    }
    #pragma unroll
    for (int i = 0; i < 4; ++i)
        #pragma unroll
        for (int j = 0; j < 4; ++j) {
            float v = 0.125f * acc[i][j];
            v = v > 0.f ? v : 0.f;
            Qb[(long)(ty * 4 + i) * CDIM + tx * 4 + j] = f2b(v);
        }
}

// ---------------------------------------------------------------------------
extern "C" void kernel_launch(void* const* d_in, const int* in_sizes, int n_in,
                              void* d_out, int out_size, void* d_ws, size_t ws_size,
                              hipStream_t stream)
{
    const void* x = d_in[0];
    const void* w[4];
    BnArgs bn;
    for (int p = 0; p < 4; ++p) {
        w[p]      = d_in[1 + 6 * p + 0];
        bn.b[p]   = d_in[1 + 6 * p + 1];
        bn.g[p]   = d_in[1 + 6 * p + 2];
        bn.be[p]  = d_in[1 + 6 * p + 3];
        bn.mu[p]  = d_in[1 + 6 * p + 4];
        bn.va[p]  = d_in[1 + 6 * p + 5];
    }

    // workspace layout (~26.2 MB total)
    char* ws = (char*)d_ws;
    float*  s_all = (float*)ws;                      // 8 KB
    float*  t_all = (float*)(ws + 8192);             // 8 KB
    int*    flag  = (int*)(ws + 16384);              // 16 B
    ushort* Qw    = (ushort*)(ws + 16400);           // 8 MB
    ushort* Kw    = Qw + (long)MROWS * CDIM;         // 8 MB
    ushort* Vw    = Kw + (long)MROWS * CDIM;         // 8 MB
    float*  S     = (float*)(ws + 16400 + 3L * MROWS * CDIM * 2);  // 1 MB fp32

    detect_kernel<<<1, 256, 0, stream>>>((const ushort*)x, flag);
    prep_st_kernel<<<8, 256, 0, stream>>>(bn, s_all, t_all, flag);

    // Q/K/V = relu(bn(x @ w^T))
    gemm_valu<<<dim3(128, 8), 256, 0, stream>>>(x, w[0], Qw, s_all, t_all, 0,    flag, 1, 0);
    gemm_valu<<<dim3(128, 8), 256, 0, stream>>>(x, w[1], Kw, s_all, t_all, 512,  flag, 1, 0);
    gemm_valu<<<dim3(128, 8), 256, 0, stream>>>(x, w[2], Vw, s_all, t_all, 1024, flag, 1, 0);

    // S = K^T V per (b,h)
    ktv_kernel<<<64, 256, 0, stream>>>(Kw, Vw, S);

    // Q <- relu(SCALE * Q @ S)   (in place)
    attn_kernel<<<dim3(64, 16), 256, 0, stream>>>(Qw, S);

    // out = relu(bn(attn_out @ p_w^T))
    gemm_valu<<<dim3(128, 8), 256, 0, stream>>>(Qw, w[3], d_out, s_all, t_all, 1536, flag, 0, 1);
}